// Round 5
// baseline (246.354 us; speedup 1.0000x reference)
//
#include <hip/hip_runtime.h>
#include <math.h>

#define D        2048
#define E        64
#define NROWS    16384              // B*S = 4*4096

// ---------------- fused MFMA path geometry ----------------
#define ROWS_PB  16                 // token rows per block (all 4 waves share)
#define KSW      512                // K-slice per wave (4 waves cover K=2048)
#define WCVT_BYTES ((size_t)2 * E * D * sizeof(unsigned short))   // 512 KB

// lo-term scaling: lo' = (v - fp16(v)) * 2^11  (keeps lo in fp16 NORMAL range).
// Recombine with 2^-11 / 2^-22.
#define LSCALE   2048.0f
#define S1       4.8828125e-4f            // 2^-11
#define S2       2.384185791015625e-7f    // 2^-22

typedef __attribute__((ext_vector_type(8))) _Float16 f16x8;
typedef __attribute__((ext_vector_type(4))) float f32x4;

union u4h8 { uint4 u; f16x8 h; };

__device__ __forceinline__ unsigned short f2h(float f) {
    union { _Float16 h; unsigned short u; } c;
    c.h = (_Float16)f;                 // v_cvt_f16_f32, RNE
    return c.u;
}
__device__ __forceinline__ float h2f(unsigned short u) {
    union { _Float16 h; unsigned short u; } c;
    c.u = u;
    return (float)c.h;
}

__device__ __forceinline__ f16x8 ld_b16(const unsigned short* p) {
    u4h8 c; c.u = *(const uint4*)p; return c.h;
}

// scale + split 8 consecutive fp32 into fp16 hi / lo' fragments (in-register)
__device__ __forceinline__ void split8(float4 A, float4 B, float f,
                                       f16x8& hi, f16x8& lo) {
    float v[8] = {A.x * f, A.y * f, A.z * f, A.w * f,
                  B.x * f, B.y * f, B.z * f, B.w * f};
    unsigned int hw[4], lw[4];
#pragma unroll
    for (int j = 0; j < 4; ++j) {
        const unsigned short h0 = f2h(v[2*j]);
        const unsigned short h1 = f2h(v[2*j+1]);
        const unsigned short l0 = f2h((v[2*j]   - h2f(h0)) * LSCALE);
        const unsigned short l1 = f2h((v[2*j+1] - h2f(h1)) * LSCALE);
        hw[j] = (unsigned int)h0 | ((unsigned int)h1 << 16);
        lw[j] = (unsigned int)l0 | ((unsigned int)l1 << 16);
    }
    u4h8 ch; ch.u = make_uint4(hw[0], hw[1], hw[2], hw[3]); hi = ch.h;
    u4h8 cl; cl.u = make_uint4(lw[0], lw[1], lw[2], lw[3]); lo = cl.h;
}

// ============ K0: split W (fp32) -> W_hi, W_lo' (fp16, RNE) =================
__global__ __launch_bounds__(256)
void w_cvt(const float* __restrict__ W,
           unsigned short* __restrict__ whi,
           unsigned short* __restrict__ wlo)
{
    const int i = (blockIdx.x * 256 + threadIdx.x) << 3;
    const float4 a = *(const float4*)(W + i);
    const float4 b = *(const float4*)(W + i + 4);
    float vv[8] = {a.x, a.y, a.z, a.w, b.x, b.y, b.z, b.w};
    unsigned int hw[4], lw[4];
#pragma unroll
    for (int j = 0; j < 4; ++j) {
        const unsigned short h0 = f2h(vv[2*j]);
        const unsigned short h1 = f2h(vv[2*j+1]);
        const unsigned short l0 = f2h((vv[2*j]   - h2f(h0)) * LSCALE);
        const unsigned short l1 = f2h((vv[2*j+1] - h2f(h1)) * LSCALE);
        hw[j] = (unsigned int)h0 | ((unsigned int)h1 << 16);
        lw[j] = (unsigned int)l0 | ((unsigned int)l1 << 16);
    }
    *(uint4*)(whi + i) = make_uint4(hw[0], hw[1], hw[2], hw[3]);
    *(uint4*)(wlo + i) = make_uint4(lw[0], lw[1], lw[2], lw[3]);
}

// ============ K1: deep-pipelined fp16-split MFMA GEMM + softmax + top2 ======
// Grid 1024 x 256 thr (4 waves). Same verified math/mapping as r4:
// waves own disjoint K-quarters (512), lane (fr,fq): A = x[row fr][k+8fq..+8],
// B = W[expert ct*16+fr][k+8fq..+8]; partial logits reduced in LDS at end.
// NEW: register pipeline. x is "slurped" a K-quarter (128) at a time — 8
// independent float4 loads issued back-to-back (8 KB/wave in flight) so the
// x stream runs at memory rate; B fragments use 2-set ping-pong prefetch
// issued ~2 MSTEPs before use so L2 latency is off the critical path.
// VGPR ~230 -> 2 waves/SIMD (deep-ILP trade, launch_bounds caps at 256).
__global__ __launch_bounds__(256, 2)
void moe_fused(const float* __restrict__ x,
               const unsigned short* __restrict__ whi,
               const unsigned short* __restrict__ wlo,
               const float* __restrict__ scond,
               const int* __restrict__ sidx,
               const float* __restrict__ noise,
               float* __restrict__ dispatch,
               float* __restrict__ probs,
               float* __restrict__ sel)
{
    __shared__ float lgs[4 * 16 * 68];          // 4 slices x [16][68] = 17408 B

    const int t = threadIdx.x;
    const int l = t & 63;
    const int w = t >> 6;

    const float factor = 1.0f + 0.1f * scond[sidx[0]];

    const int fr = l & 15;                       // fragment row lane
    const int fq = l >> 4;                       // fragment k-quad lane
    const int rowG0 = blockIdx.x * ROWS_PB;
    const int kb = w << 9;                       // wave K-base: w*512

    const float* xg = x + (size_t)(rowG0 + fr) * D + kb + (fq << 3);
    const unsigned short* bgh = whi + fr * D + kb + (fq << 3);
    const unsigned short* bgl = wlo + fr * D + kb + (fq << 3);

    f32x4 acch[4], accm[4], accl[4];
#pragma unroll
    for (int ct = 0; ct < 4; ++ct) {
        acch[ct] = (f32x4){0.f,0.f,0.f,0.f};
        accm[ct] = (f32x4){0.f,0.f,0.f,0.f};
        accl[ct] = (f32x4){0.f,0.f,0.f,0.f};
    }

    float4 xr[8];                    // one K-quarter (128) in flight
    f16x8 fAh[4], fAl[4], fBh[4], fBl[4];     // frag double-set
    f16x8 B0h[4], B0l[4], B1h[4], B1l[4];     // B ping-pong sets

    // issue 8 independent loads of quarter Q back-to-back (8 KB in flight)
#define SLURP(Q) do { \
    _Pragma("unroll") \
    for (int s_ = 0; s_ < 4; ++s_) { \
        xr[2*s_]   = *(const float4*)(xg + (Q)*128 + 32*s_); \
        xr[2*s_+1] = *(const float4*)(xg + (Q)*128 + 32*s_ + 4); \
    } } while(0)

#define SPLIT4(AH, AL) do { \
    _Pragma("unroll") \
    for (int s_ = 0; s_ < 4; ++s_) \
        split8(xr[2*s_], xr[2*s_+1], factor, AH[s_], AL[s_]); } while(0)

    // load B fragments (4 col-tiles, hi+lo) for global kstep KS (0..15)
#define LOADB(BH, BL, KS) do { \
    _Pragma("unroll") \
    for (int ct_ = 0; ct_ < 4; ++ct_) { \
        BH[ct_] = ld_b16(bgh + ct_ * (16 * D) + (KS) * 32); \
        BL[ct_] = ld_b16(bgl + ct_ * (16 * D) + (KS) * 32); } } while(0)

#define MSTEP(AH, AL, BH, BL) do { \
    _Pragma("unroll") \
    for (int ct_ = 0; ct_ < 4; ++ct_) { \
        acch[ct_] = __builtin_amdgcn_mfma_f32_16x16x32_f16(AH, BH[ct_], acch[ct_], 0, 0, 0); \
        accm[ct_] = __builtin_amdgcn_mfma_f32_16x16x32_f16(AH, BL[ct_], accm[ct_], 0, 0, 0); \
        accm[ct_] = __builtin_amdgcn_mfma_f32_16x16x32_f16(AL, BH[ct_], accm[ct_], 0, 0, 0); \
        accl[ct_] = __builtin_amdgcn_mfma_f32_16x16x32_f16(AL, BL[ct_], accl[ct_], 0, 0, 0); } } while(0)

    SLURP(0);
    SPLIT4(fAh, fAl);                 // wait + convert quarter 0
    SLURP(1);                         // quarter 1 in flight over q0 compute
    LOADB(B0h, B0l, 0);
    LOADB(B1h, B1l, 1);

    // ---- q0: frags fA, ksteps 0-3 ----
    MSTEP(fAh[0], fAl[0], B0h, B0l);  LOADB(B0h, B0l, 2);
    MSTEP(fAh[1], fAl[1], B1h, B1l);  LOADB(B1h, B1l, 3);
    SPLIT4(fBh, fBl);                 // convert q1
    SLURP(2);                         // q2 in flight
    MSTEP(fAh[2], fAl[2], B0h, B0l);  LOADB(B0h, B0l, 4);
    MSTEP(fAh[3], fAl[3], B1h, B1l);  LOADB(B1h, B1l, 5);
    // ---- q1: frags fB, ksteps 4-7 ----
    MSTEP(fBh[0], fBl[0], B0h, B0l);  LOADB(B0h, B0l, 6);
    MSTEP(fBh[1], fBl[1], B1h, B1l);  LOADB(B1h, B1l, 7);
    SPLIT4(fAh, fAl);                 // convert q2
    SLURP(3);                         // q3 in flight
    MSTEP(fBh[2], fBl[2], B0h, B0l);  LOADB(B0h, B0l, 8);
    MSTEP(fBh[3], fBl[3], B1h, B1l);  LOADB(B1h, B1l, 9);
    // ---- q2: frags fA, ksteps 8-11 ----
    MSTEP(fAh[0], fAl[0], B0h, B0l);  LOADB(B0h, B0l, 10);
    MSTEP(fAh[1], fAl[1], B1h, B1l);  LOADB(B1h, B1l, 11);
    SPLIT4(fBh, fBl);                 // convert q3
    MSTEP(fAh[2], fAl[2], B0h, B0l);  LOADB(B0h, B0l, 12);
    MSTEP(fAh[3], fAl[3], B1h, B1l);  LOADB(B1h, B1l, 13);
    // ---- q3: frags fB, ksteps 12-15 ----
    MSTEP(fBh[0], fBl[0], B0h, B0l);  LOADB(B0h, B0l, 14);
    MSTEP(fBh[1], fBl[1], B1h, B1l);  LOADB(B1h, B1l, 15);
    MSTEP(fBh[2], fBl[2], B0h, B0l);
    MSTEP(fBh[3], fBl[3], B1h, B1l);

#undef SLURP
#undef SPLIT4
#undef LOADB
#undef MSTEP

    // ---- per-wave partial logits -> own LDS slice (verified C/D mapping) ----
    float* slice = lgs + w * (16 * 68);
#pragma unroll
    for (int ct = 0; ct < 4; ++ct)
#pragma unroll
        for (int j = 0; j < 4; ++j)
            slice[((fq << 2) + j) * 68 + (ct << 4) + fr] =
                acch[ct][j] + S1 * accm[ct][j] + S2 * accl[ct][j];

    __syncthreads();

    // ---- reduce 4 K-slices (owner thread: row t>>4, cols (t&15)*4..+4) ----
    {
        const int o = (t >> 4) * 68 + ((t & 15) << 2);
        const float4 v0 = *(const float4*)&lgs[o];
        const float4 v1 = *(const float4*)&lgs[1 * 16 * 68 + o];
        const float4 v2 = *(const float4*)&lgs[2 * 16 * 68 + o];
        const float4 v3 = *(const float4*)&lgs[3 * 16 * 68 + o];
        float4 r;
        r.x = (v0.x + v1.x) + (v2.x + v3.x);
        r.y = (v0.y + v1.y) + (v2.y + v3.y);
        r.z = (v0.z + v1.z) + (v2.z + v3.z);
        r.w = (v0.w + v1.w) + (v2.w + v3.w);
        *(float4*)&lgs[o] = r;                   // owner-only read+write: safe
    }
    __syncthreads();

    // ---- verified softmax/top-2 epilogue: 4 rows per wave ----
    const int r0 = w << 2;
#pragma unroll
    for (int i = 0; i < 4; ++i) {
        const int G = rowG0 + r0 + i;
        const float v = lgs[(r0 + i) * 68 + l] + 0.1f * noise[(size_t)G * E + l];

        float m = v;
#pragma unroll
        for (int off = 32; off > 0; off >>= 1)
            m = fmaxf(m, __shfl_xor(m, off, 64));
        const float p = expf(v - m);
        float s = p;
#pragma unroll
        for (int off = 32; off > 0; off >>= 1)
            s += __shfl_xor(s, off, 64);
        const float prob = p / s;
        probs[(size_t)G * E + l] = prob;

        float bv = prob; int bi = l;
#pragma unroll
        for (int off = 32; off > 0; off >>= 1) {
            const float ov = __shfl_xor(bv, off, 64);
            const int   oi = __shfl_xor(bi, off, 64);
            if (ov > bv || (ov == bv && oi < bi)) { bv = ov; bi = oi; }
        }
        float cv = (l == bi) ? -INFINITY : prob;
        int ci = l;
#pragma unroll
        for (int off = 32; off > 0; off >>= 1) {
            const float ov = __shfl_xor(cv, off, 64);
            const int   oi = __shfl_xor(ci, off, 64);
            if (ov > cv || (ov == cv && oi < ci)) { cv = ov; ci = oi; }
        }

        const float sum2 = bv + cv;
        float dval = 0.f;
        if (l == bi) dval = bv / sum2;
        if (l == ci) dval = cv / sum2;
        dispatch[(size_t)G * E + l] = dval;

        if (l == 0) {
            float2 sv; sv.x = (float)bi; sv.y = (float)ci;
            *(float2*)(sel + (size_t)G * 2) = sv;
        }
    }
}

// ================== Fallback pair (round-2, known-good) =====================
__global__ __launch_bounds__(256)
void gemm_r2(const float* __restrict__ x, const float* __restrict__ W,
             const float* __restrict__ scond, const float* __restrict__ noise,
             const int* __restrict__ sidx, float* __restrict__ logits_out)
{
    __shared__ float4 xsb[32][17];
    __shared__ float4 wsh[64][16];
    const int tid = threadIdx.x;
    const int rowBase = blockIdx.x * 32;
    const float factor = 1.0f + 0.1f * scond[sidx[0]];
    const int xk = tid & 15, xr = tid >> 4, we = tid & 63, wk = tid >> 6;
    const int eg = tid & 15, rg = tid >> 4, e0 = eg << 2;
    float acc[2][4];
#pragma unroll
    for (int i = 0; i < 2; ++i)
#pragma unroll
        for (int j = 0; j < 4; ++j) acc[i][j] = 0.f;
    const float* xg = x + (size_t)rowBase * D;
    float4 xb[2], wb[4];
#pragma unroll
    for (int i = 0; i < 2; ++i)
        xb[i] = *(const float4*)(xg + (xr + 16 * i) * D + (xk << 2));
#pragma unroll
    for (int j = 0; j < 4; ++j)
        wb[j] = *(const float4*)(W + we * D + (wk << 4) + (j << 2));
    for (int t = 0; t < 32; ++t) {
#pragma unroll
        for (int i = 0; i < 2; ++i) {
            float4 v = xb[i];
            v.x *= factor; v.y *= factor; v.z *= factor; v.w *= factor;
            xsb[xr + 16 * i][xk] = v;
        }
        float* wsf = (float*)wsh;
#pragma unroll
        for (int j = 0; j < 4; ++j) {
            const int kk = (wk << 4) + (j << 2);
            wsf[(kk + 0) * E + we] = wb[j].x;
            wsf[(kk + 1) * E + we] = wb[j].y;
            wsf[(kk + 2) * E + we] = wb[j].z;
            wsf[(kk + 3) * E + we] = wb[j].w;
        }
        __syncthreads();
        if (t + 1 < 32) {
            const int k0 = (t + 1) * 64;
#pragma unroll
            for (int i = 0; i < 2; ++i)
                xb[i] = *(const float4*)(xg + (xr + 16 * i) * D + k0 + (xk << 2));
#pragma unroll
            for (int j = 0; j < 4; ++j)
                wb[j] = *(const float4*)(W + we * D + k0 + (wk << 4) + (j << 2));
        }
#pragma unroll
        for (int kg = 0; kg < 16; ++kg) {
            float4 xv[2], wv[4];
#pragma unroll
            for (int i = 0; i < 2; ++i) xv[i] = xsb[rg + 16 * i][kg];
#pragma unroll
            for (int c = 0; c < 4; ++c) wv[c] = wsh[(kg << 2) + c][eg];
#pragma unroll
            for (int i = 0; i < 2; ++i) {
                const float x0 = xv[i].x, x1 = xv[i].y, x2 = xv[i].z, x3 = xv[i].w;
                acc[i][0] += x0 * wv[0].x; acc[i][1] += x0 * wv[0].y;
                acc[i][2] += x0 * wv[0].z; acc[i][3] += x0 * wv[0].w;
                acc[i][0] += x1 * wv[1].x; acc[i][1] += x1 * wv[1].y;
                acc[i][2] += x1 * wv[1].z; acc[i][3] += x1 * wv[1].w;
                acc[i][0] += x2 * wv[2].x; acc[i][1] += x2 * wv[2].y;
                acc[i][2] += x2 * wv[2].z; acc[i][3] += x2 * wv[2].w;
                acc[i][0] += x3 * wv[3].x; acc[i][1] += x3 * wv[3].y;
                acc[i][2] += x3 * wv[3].z; acc[i][3] += x3 * wv[3].w;
            }
        }
        __syncthreads();
    }
#pragma unroll
    for (int i = 0; i < 2; ++i) {
        const int gRow = rowBase + rg + 16 * i;
        const float4 nz = *(const float4*)(noise + (size_t)gRow * E + e0);
        float4 o;
        o.x = acc[i][0] + 0.1f * nz.x; o.y = acc[i][1] + 0.1f * nz.y;
        o.z = acc[i][2] + 0.1f * nz.z; o.w = acc[i][3] + 0.1f * nz.w;
        *(float4*)(logits_out + (size_t)gRow * E + e0) = o;
    }
}

__global__ __launch_bounds__(256)
void topk_r2(float* __restrict__ probs, float* __restrict__ dispatch,
             float* __restrict__ sel)
{
    const int lane = threadIdx.x & 63;
    const int wave = threadIdx.x >> 6;
    const int row  = blockIdx.x * 4 + wave;
    const float v = probs[(size_t)row * E + lane];
    float m = v;
#pragma unroll
    for (int off = 32; off > 0; off >>= 1)
        m = fmaxf(m, __shfl_xor(m, off, 64));
    const float p = expf(v - m);
    float s = p;
#pragma unroll
    for (int off = 32; off > 0; off >>= 1)
        s += __shfl_xor(s, off, 64);
    const float prob = p / s;
    probs[(size_t)row * E + lane] = prob;
    float bv = prob; int bi = lane;
#pragma unroll
    for (int off = 32; off > 0; off >>= 1) {
        const float ov = __shfl_xor(bv, off, 64);
        const int   oi = __shfl_xor(bi, off, 64);
        if (ov > bv || (ov == bv && oi < bi)) { bv = ov; bi = oi; }
    }
    float cv = (lane == bi) ? -INFINITY : prob;
    int ci = lane;
#pragma unroll
    for (int off = 32; off > 0; off >>= 1) {
        const float ov = __shfl_xor(cv, off, 64);
        const int   oi = __shfl_xor(ci, off, 64);
        if (ov > cv || (ov == cv && oi < ci)) { cv = ov; ci = oi; }
    }
    const float sum2 = bv + cv;
    float dval = 0.f;
    if (lane == bi) dval = bv / sum2;
    if (lane == ci) dval = cv / sum2;
    dispatch[(size_t)row * E + lane] = dval;
    if (lane == 0) {
        float2 sv; sv.x = (float)bi; sv.y = (float)ci;
        *(float2*)(sel + (size_t)row * 2) = sv;
    }
}

extern "C" void kernel_launch(void* const* d_in, const int* in_sizes, int n_in,
                              void* d_out, int out_size, void* d_ws, size_t ws_size,
                              hipStream_t stream) {
    const float* x     = (const float*)d_in[0];
    const float* W     = (const float*)d_in[1];
    const float* scond = (const float*)d_in[2];
    const float* noise = (const float*)d_in[3];
    const int*   sidx  = (const int*)d_in[4];

    float* out      = (float*)d_out;
    float* dispatch = out;
    float* probs    = out + (size_t)NROWS * E;
    float* sel      = out + 2 * (size_t)NROWS * E;

    if (ws_size >= WCVT_BYTES) {
        unsigned short* whi = (unsigned short*)d_ws;
        unsigned short* wlo = whi + (size_t)E * D;
        w_cvt<<<dim3(64), dim3(256), 0, stream>>>(W, whi, wlo);
        moe_fused<<<dim3(NROWS / ROWS_PB), dim3(256), 0, stream>>>(
            x, whi, wlo, scond, sidx, noise, dispatch, probs, sel);
    } else {
        gemm_r2<<<dim3(NROWS / 32), dim3(256), 0, stream>>>(
            x, W, scond, noise, sidx, probs);
        topk_r2<<<dim3(NROWS / 4), dim3(256), 0, stream>>>(
            probs, dispatch, sel);
    }
}

// Round 6
// 228.047 us; speedup vs baseline: 1.0803x; 1.0803x over previous
//
#include <hip/hip_runtime.h>
#include <math.h>

#define D        2048
#define E        64
#define NROWS    16384              // B*S = 4*4096

// ---------------- fused MFMA path geometry (r2-verified structure) ----------
#define ROWS_PB  32                 // token rows per block
#define BKC      64                 // K per chunk
#define NCH      (D / BKC)          // 32 chunks
#define LDX      72                 // LDS row stride (fp16 elems) for x tiles
#define LDW      72                 // LDS row stride (fp16 elems) for W tiles
#define XSH      (ROWS_PB * LDX)    // 2304 shorts (one of hi/lo)
#define WSH      (E * LDW)          // 4608 shorts (one of hi/lo)
#define BUF_SHORTS (2 * XSH + 2 * WSH)   // 13824 shorts per buffer
// 2 buffers = 27648 shorts = 55296 B -> 2 blocks/CU, 16 waves/CU

// lo-term scaling: lo' = (v - fp16(v)) * 2^11  (keeps lo in fp16 NORMAL range).
// Recombine with 2^-11 / 2^-22.
#define LSCALE   2048.0f
#define S1       4.8828125e-4f            // 2^-11
#define S2       2.384185791015625e-7f    // 2^-22

typedef __attribute__((ext_vector_type(8))) _Float16 f16x8;
typedef __attribute__((ext_vector_type(4))) float f32x4;

// W hi/lo split lives in MODULE GLOBALS (512 KB .bss) — d_ws is never touched,
// so the harness's 512 MiB workspace poison-fill (78 us x2 per iteration in
// every profile so far) has nothing to poison on our account.
__device__ unsigned short g_whi[(size_t)E * D];
__device__ unsigned short g_wlo[(size_t)E * D];

__device__ __forceinline__ unsigned short f2h(float f) {
    union { _Float16 h; unsigned short u; } c;
    c.h = (_Float16)f;                 // v_cvt_f16_f32, RNE
    return c.u;
}
__device__ __forceinline__ float h2f(unsigned short u) {
    union { _Float16 h; unsigned short u; } c;
    c.u = u;
    return (float)c.h;
}

// ============ K0: split W (fp32) -> g_whi, g_wlo' (fp16, RNE) ===============
__global__ __launch_bounds__(256)
void w_cvt(const float* __restrict__ W)
{
    const int i = (blockIdx.x * 256 + threadIdx.x) << 3;
    const float4 a = *(const float4*)(W + i);
    const float4 b = *(const float4*)(W + i + 4);
    float vv[8] = {a.x, a.y, a.z, a.w, b.x, b.y, b.z, b.w};
    unsigned int hw[4], lw[4];
#pragma unroll
    for (int j = 0; j < 4; ++j) {
        const unsigned short h0 = f2h(vv[2*j]);
        const unsigned short h1 = f2h(vv[2*j+1]);
        const unsigned short l0 = f2h((vv[2*j]   - h2f(h0)) * LSCALE);
        const unsigned short l1 = f2h((vv[2*j+1] - h2f(h1)) * LSCALE);
        hw[j] = (unsigned int)h0 | ((unsigned int)h1 << 16);
        lw[j] = (unsigned int)l0 | ((unsigned int)l1 << 16);
    }
    *(uint4*)(g_whi + i) = make_uint4(hw[0], hw[1], hw[2], hw[3]);
    *(uint4*)(g_wlo + i) = make_uint4(lw[0], lw[1], lw[2], lw[3]);
}

// ============ K1: fused fp16-split MFMA GEMM + softmax + top2 ===============
// Grid 512 x 512 thr (8 waves; 2 blocks/CU -> 16 waves/CU, 4/SIMD).
// r2-verified schedule: stage(regs->LDS) -> barrier -> prefetch(next) ->
// compute; double-buffered so one barrier per chunk is race-free.
// Wave w owns rows [(w>>2)*16,+16) x experts [(w&3)*16,+16) — ONE col-tile
// (3 accumulators h/m/l), half the per-wave work of r2 but 2x the waves.
// All fragment/LDS/epilogue mappings identical to the r1/r2-verified ones.
__global__ __launch_bounds__(512, 4)
void moe_fused(const float* __restrict__ x,
               const float* __restrict__ scond,
               const int* __restrict__ sidx,
               const float* __restrict__ noise,
               float* __restrict__ dispatch,
               float* __restrict__ probs,
               float* __restrict__ sel)
{
    __shared__ unsigned short smem[2 * BUF_SHORTS];   // 55296 B

    const int t = threadIdx.x;
    const int l = t & 63;
    const int w = t >> 6;

    const float factor = 1.0f + 0.1f * scond[sidx[0]];

    // staging maps (512 threads)
    const int xr_ = t >> 4;             // 0..31 token row
    const int xc_ = (t & 15) << 2;      // 0..60 k col (floats)
    const int we_ = t >> 3;             // 0..63 expert row
    const int wk_ = (t & 7) << 3;       // 0..56 k col (shorts)

    // wave / fragment maps (verified)
    const int R  = (w >> 2) << 4;       // wave row base: 0 / 16
    const int CB = (w & 3) << 4;        // wave expert base: 0/16/32/48
    const int fr = l & 15;
    const int fq = l >> 4;

    const int rowG0 = blockIdx.x * ROWS_PB;

    const float* xg = x + (size_t)(rowG0 + xr_) * D + xc_;
    const unsigned short* wgh = g_whi + (size_t)we_ * D + wk_;
    const unsigned short* wgl = g_wlo + (size_t)we_ * D + wk_;

    f32x4 acch = {0.f,0.f,0.f,0.f};
    f32x4 accm = {0.f,0.f,0.f,0.f};
    f32x4 accl = {0.f,0.f,0.f,0.f};

    // prefetch chunk 0
    float4 xp  = *(const float4*)(xg);
    uint4  wph = *(const uint4*)(wgh);
    uint4  wpl = *(const uint4*)(wgl);

    for (int c = 0; c < NCH; ++c) {
        unsigned short* base = smem + (c & 1) * BUF_SHORTS;
        unsigned short* xh = base;
        unsigned short* xl = base + XSH;
        unsigned short* wh = base + 2 * XSH;
        unsigned short* wl = wh + WSH;

        // ---- stage x: scale, split to fp16 hi/lo', 2x uint2 writes ----
        {
            const float v0 = xp.x * factor, v1 = xp.y * factor;
            const float v2 = xp.z * factor, v3 = xp.w * factor;
            const unsigned short h0 = f2h(v0), h1 = f2h(v1);
            const unsigned short h2 = f2h(v2), h3 = f2h(v3);
            const unsigned short q0 = f2h((v0 - h2f(h0)) * LSCALE);
            const unsigned short q1 = f2h((v1 - h2f(h1)) * LSCALE);
            const unsigned short q2 = f2h((v2 - h2f(h2)) * LSCALE);
            const unsigned short q3 = f2h((v3 - h2f(h3)) * LSCALE);
            uint2 hw, lw;
            hw.x = (unsigned int)h0 | ((unsigned int)h1 << 16);
            hw.y = (unsigned int)h2 | ((unsigned int)h3 << 16);
            lw.x = (unsigned int)q0 | ((unsigned int)q1 << 16);
            lw.y = (unsigned int)q2 | ((unsigned int)q3 << 16);
            const int o = xr_ * LDX + xc_;
            *(uint2*)&xh[o] = hw;
            *(uint2*)&xl[o] = lw;
        }
        // ---- stage W (already fp16 in globals): 2x uint4 writes ----
        {
            const int o = we_ * LDW + wk_;
            *(uint4*)&wh[o] = wph;
            *(uint4*)&wl[o] = wpl;
        }

        __syncthreads();

        // prefetch chunk c+1 (in flight across the compute phase)
        if (c + 1 < NCH) {
            const int kn = (c + 1) * BKC;
            xp  = *(const float4*)(xg + kn);
            wph = *(const uint4*)(wgh + kn);
            wpl = *(const uint4*)(wgl + kn);
        }

        // ---- MFMA: 2 k-steps x (4 ds_read_b128 + 4 mfma) ----
#pragma unroll
        for (int ks = 0; ks < 2; ++ks) {
            const int ko = (ks << 5) + (fq << 3);
            const f16x8 ah = *(const f16x8*)&xh[(R + fr) * LDX + ko];
            const f16x8 al = *(const f16x8*)&xl[(R + fr) * LDX + ko];
            const f16x8 bh = *(const f16x8*)&wh[(CB + fr) * LDW + ko];
            const f16x8 bl = *(const f16x8*)&wl[(CB + fr) * LDW + ko];
            acch = __builtin_amdgcn_mfma_f32_16x16x32_f16(ah, bh, acch, 0, 0, 0);
            accm = __builtin_amdgcn_mfma_f32_16x16x32_f16(ah, bl, accm, 0, 0, 0);
            accm = __builtin_amdgcn_mfma_f32_16x16x32_f16(al, bh, accm, 0, 0, 0);
            accl = __builtin_amdgcn_mfma_f32_16x16x32_f16(al, bl, accl, 0, 0, 0);
        }
    }

    // ---- epilogue: logits -> LDS [32][68] f32, then per-wave 4 rows ----
    __syncthreads();                       // buffers dead; alias as float
    float* lg = (float*)smem;
#pragma unroll
    for (int j = 0; j < 4; ++j) {
        const int rr = R + (fq << 2) + j;  // token row within 32-row tile
        lg[rr * 68 + CB + fr] = acch[j] + S1 * accm[j] + S2 * accl[j];
    }
    __syncthreads();

    const int r0 = w << 2;                 // 4 rows per wave (8 waves x 4 = 32)
#pragma unroll
    for (int i = 0; i < 4; ++i) {
        const int G = rowG0 + r0 + i;
        const float v = lg[(r0 + i) * 68 + l] + 0.1f * noise[(size_t)G * E + l];

        float m = v;
#pragma unroll
        for (int off = 32; off > 0; off >>= 1)
            m = fmaxf(m, __shfl_xor(m, off, 64));
        const float p = expf(v - m);
        float s = p;
#pragma unroll
        for (int off = 32; off > 0; off >>= 1)
            s += __shfl_xor(s, off, 64);
        const float prob = p / s;
        probs[(size_t)G * E + l] = prob;

        float bv = prob; int bi = l;
#pragma unroll
        for (int off = 32; off > 0; off >>= 1) {
            const float ov = __shfl_xor(bv, off, 64);
            const int   oi = __shfl_xor(bi, off, 64);
            if (ov > bv || (ov == bv && oi < bi)) { bv = ov; bi = oi; }
        }
        float cv = (l == bi) ? -INFINITY : prob;
        int ci = l;
#pragma unroll
        for (int off = 32; off > 0; off >>= 1) {
            const float ov = __shfl_xor(cv, off, 64);
            const int   oi = __shfl_xor(ci, off, 64);
            if (ov > cv || (ov == cv && oi < ci)) { cv = ov; ci = oi; }
        }

        const float sum2 = bv + cv;
        float dval = 0.f;
        if (l == bi) dval = bv / sum2;
        if (l == ci) dval = cv / sum2;
        dispatch[(size_t)G * E + l] = dval;

        if (l == 0) {
            float2 sv; sv.x = (float)bi; sv.y = (float)ci;
            *(float2*)(sel + (size_t)G * 2) = sv;
        }
    }
}

extern "C" void kernel_launch(void* const* d_in, const int* in_sizes, int n_in,
                              void* d_out, int out_size, void* d_ws, size_t ws_size,
                              hipStream_t stream) {
    const float* x     = (const float*)d_in[0];
    const float* W     = (const float*)d_in[1];
    const float* scond = (const float*)d_in[2];
    const float* noise = (const float*)d_in[3];
    const int*   sidx  = (const int*)d_in[4];

    float* out      = (float*)d_out;
    float* dispatch = out;
    float* probs    = out + (size_t)NROWS * E;
    float* sel      = out + 2 * (size_t)NROWS * E;

    // d_ws deliberately unused: W split lives in module globals (512 KB),
    // recomputed every launch by w_cvt before moe_fused consumes it.
    (void)d_ws; (void)ws_size;

    w_cvt<<<dim3(64), dim3(256), 0, stream>>>(W);
    moe_fused<<<dim3(NROWS / ROWS_PB), dim3(512), 0, stream>>>(
        x, scond, sidx, noise, dispatch, probs, sel);
}

// Round 7
// 224.498 us; speedup vs baseline: 1.0974x; 1.0158x over previous
//
#include <hip/hip_runtime.h>
#include <math.h>

#define D        2048
#define E        64
#define NROWS    16384              // B*S = 4*4096

// ---------------- fused MFMA path geometry ----------------
#define ROWS_PB  32                 // token rows per block
#define BKC      64                 // K per chunk
#define NCH      (D / BKC)          // 32 chunks
// LDS per buffer (bytes): x fp32 [32][64] = 8192 | Whi fp16 [64][64] = 8192 |
//                         Wlo fp16 [64][64] = 8192   => 24576
#define XOFF     0
#define WHOFF    8192
#define WLOFF    16384
#define BUFB     24576
// 2 buffers = 49152 B -> 2 blocks/CU (16 waves/CU), 48 KB DMA in flight/CU

// lo-term scaling: lo' = (v - fp16(v)) * 2^11 (keeps lo in fp16 NORMAL range).
// Recombine with 2^-11 / 2^-22.
#define LSCALE   2048.0f
#define S1       4.8828125e-4f            // 2^-11
#define S2       2.384185791015625e-7f    // 2^-22

typedef __attribute__((ext_vector_type(8))) _Float16 f16x8;
typedef __attribute__((ext_vector_type(4))) float f32x4;

// W hi/lo split in module globals (512 KB) — d_ws never touched.
__device__ __attribute__((aligned(16))) unsigned short g_whi[(size_t)E * D];
__device__ __attribute__((aligned(16))) unsigned short g_wlo[(size_t)E * D];

__device__ __forceinline__ unsigned short f2h(float f) {
    union { _Float16 h; unsigned short u; } c;
    c.h = (_Float16)f;                 // v_cvt_f16_f32, RNE
    return c.u;
}
__device__ __forceinline__ float h2f(unsigned short u) {
    union { _Float16 h; unsigned short u; } c;
    c.u = u;
    return (float)c.h;
}

// async global->LDS DMA, 16 B/lane. LDS dest is WAVE-UNIFORM base + lane*16;
// global src is per-lane (carries the swizzle). Counted by vmcnt.
__device__ __forceinline__ void dma16(const void* g, void* l) {
    __builtin_amdgcn_global_load_lds(
        (const __attribute__((address_space(1))) unsigned int*)g,
        (__attribute__((address_space(3))) unsigned int*)l,
        16, 0, 0);
}

// scale + split 8 consecutive fp32 into fp16 hi / lo' fragments (in-register)
__device__ __forceinline__ void split8(float4 A, float4 B, float f,
                                       f16x8& hi, f16x8& lo) {
    float v[8] = {A.x * f, A.y * f, A.z * f, A.w * f,
                  B.x * f, B.y * f, B.z * f, B.w * f};
    unsigned int hw[4], lw[4];
#pragma unroll
    for (int j = 0; j < 4; ++j) {
        const unsigned short h0 = f2h(v[2*j]);
        const unsigned short h1 = f2h(v[2*j+1]);
        const unsigned short l0 = f2h((v[2*j]   - h2f(h0)) * LSCALE);
        const unsigned short l1 = f2h((v[2*j+1] - h2f(h1)) * LSCALE);
        hw[j] = (unsigned int)h0 | ((unsigned int)h1 << 16);
        lw[j] = (unsigned int)l0 | ((unsigned int)l1 << 16);
    }
    union { uint4 u; f16x8 h; } ch, cl;
    ch.u = make_uint4(hw[0], hw[1], hw[2], hw[3]); hi = ch.h;
    cl.u = make_uint4(lw[0], lw[1], lw[2], lw[3]); lo = cl.h;
}

// ============ K0: split W (fp32) -> g_whi, g_wlo' (fp16, RNE) ===============
__global__ __launch_bounds__(256)
void w_cvt(const float* __restrict__ W)
{
    const int i = (blockIdx.x * 256 + threadIdx.x) << 3;
    const float4 a = *(const float4*)(W + i);
    const float4 b = *(const float4*)(W + i + 4);
    float vv[8] = {a.x, a.y, a.z, a.w, b.x, b.y, b.z, b.w};
    unsigned int hw[4], lw[4];
#pragma unroll
    for (int j = 0; j < 4; ++j) {
        const unsigned short h0 = f2h(vv[2*j]);
        const unsigned short h1 = f2h(vv[2*j+1]);
        const unsigned short l0 = f2h((vv[2*j]   - h2f(h0)) * LSCALE);
        const unsigned short l1 = f2h((vv[2*j+1] - h2f(h1)) * LSCALE);
        hw[j] = (unsigned int)h0 | ((unsigned int)h1 << 16);
        lw[j] = (unsigned int)l0 | ((unsigned int)l1 << 16);
    }
    *(uint4*)(g_whi + i) = make_uint4(hw[0], hw[1], hw[2], hw[3]);
    *(uint4*)(g_wlo + i) = make_uint4(lw[0], lw[1], lw[2], lw[3]);
}

// ============ K1: DMA-staged fp16-split MFMA GEMM + softmax + top2 ==========
// Grid 512 x 512 thr (8 waves). Per chunk: 3x global_load_lds per thread
// (x 8KB + Whi 8KB + Wlo 8KB -> 24KB/block in flight), one barrier.
// x staged RAW fp32; scale+fp16-split happens in the compute phase (VALU
// overlaps MFMA). LDS slots XOR-swizzled (slot16 ^= row&7) via pre-swizzled
// GLOBAL source (rule: both-sides-or-neither with linear DMA writes);
// reads then hit the b128 8-words/bank floor (balanced, conflict-free).
// Wave w: rows [(w>>2)*16,+16) x experts [(w&3)*16,+16); verified mappings.
__global__ __launch_bounds__(512, 4)
void moe_fused(const float* __restrict__ x,
               const float* __restrict__ scond,
               const int* __restrict__ sidx,
               const float* __restrict__ noise,
               float* __restrict__ dispatch,
               float* __restrict__ probs,
               float* __restrict__ sel)
{
    __shared__ float4 smem_q[2 * BUFB / 16];          // 49152 B
    unsigned char* const sm = (unsigned char*)smem_q;

    const int t = threadIdx.x;
    const int l = t & 63;
    const int w = t >> 6;

    const float factor = 1.0f + 0.1f * scond[sidx[0]];

    // wave / fragment maps (verified)
    const int R  = (w >> 2) << 4;       // wave row base: 0 / 16
    const int CB = (w & 3) << 4;        // wave expert base: 0/16/32/48
    const int fr = l & 15;
    const int fq = l >> 4;
    const int sw = fr & 7;              // read-side swizzle key (row&7)

    const int rowG0 = blockIdx.x * ROWS_PB;

    // DMA source bases (pre-swizzled: global col16 = physical slot ^ (row&7))
    const float* xsrc =
        x + (size_t)(rowG0 + (t >> 4)) * D + (((t & 15) ^ ((t >> 4) & 7)) << 2);
    const unsigned short* whsrc =
        g_whi + (size_t)(t >> 3) * D + (((t & 7) ^ ((t >> 3) & 7)) << 3);
    const unsigned short* wlsrc =
        g_wlo + (size_t)(t >> 3) * D + (((t & 7) ^ ((t >> 3) & 7)) << 3);

    // wave-uniform LDS dest bases (lane*16 added by HW)
    const int wb = w << 10;             // w*1024 bytes

    f32x4 acch = {0.f,0.f,0.f,0.f};
    f32x4 accm = {0.f,0.f,0.f,0.f};
    f32x4 accl = {0.f,0.f,0.f,0.f};

#define STAGE(B, CC) do { \
    unsigned char* const bb_ = sm + (B) * BUFB; \
    dma16(xsrc  + (size_t)(CC) * BKC, bb_ + XOFF  + wb); \
    dma16(whsrc + (size_t)(CC) * BKC, bb_ + WHOFF + wb); \
    dma16(wlsrc + (size_t)(CC) * BKC, bb_ + WLOFF + wb); \
} while (0)

    // prologue: stage chunk 0, drain, barrier
    STAGE(0, 0);
    asm volatile("s_waitcnt vmcnt(0)" ::: "memory");
    __syncthreads();

    for (int c = 0; c < NCH; ++c) {
        const int cur = c & 1;
        if (c + 1 < NCH) STAGE(cur ^ 1, c + 1);   // 24KB DMA in flight

        const unsigned char* bb = sm + cur * BUFB;
        const float* xb = (const float*)(bb + XOFF);                 // [32][64]
        const unsigned short* whb = (const unsigned short*)(bb + WHOFF); // [64][64]
        const unsigned short* wlb = (const unsigned short*)(bb + WLOFF);

#pragma unroll
        for (int ks = 0; ks < 2; ++ks) {
            const int ls0 = (ks << 3) + (fq << 1);     // x logical slot16
            const float4 xa = *(const float4*)(xb + ((R + fr) << 6) + ((ls0 ^ sw) << 2));
            const float4 xv = *(const float4*)(xb + ((R + fr) << 6) + (((ls0 + 1) ^ sw) << 2));
            f16x8 ah, al;
            split8(xa, xv, factor, ah, al);
            const int lw_ = (ks << 2) + fq;            // W logical slot16
            const f16x8 bh = *(const f16x8*)(whb + ((CB + fr) << 6) + ((lw_ ^ sw) << 3));
            const f16x8 bl = *(const f16x8*)(wlb + ((CB + fr) << 6) + ((lw_ ^ sw) << 3));
            acch = __builtin_amdgcn_mfma_f32_16x16x32_f16(ah, bh, acch, 0, 0, 0);
            accm = __builtin_amdgcn_mfma_f32_16x16x32_f16(ah, bl, accm, 0, 0, 0);
            accm = __builtin_amdgcn_mfma_f32_16x16x32_f16(al, bh, accm, 0, 0, 0);
            accl = __builtin_amdgcn_mfma_f32_16x16x32_f16(al, bl, accl, 0, 0, 0);
        }

        __syncthreads();    // compiler drains vmcnt(0)+lgkmcnt(0) here:
                            // next chunk's DMA is complete on exit
    }
#undef STAGE

    // ---- epilogue: logits -> LDS [32][68] f32, then per-wave 4 rows ----
    float* lg = (float*)sm;                    // buffers dead; alias as float
#pragma unroll
    for (int j = 0; j < 4; ++j) {
        const int rr = R + (fq << 2) + j;      // token row within 32-row tile
        lg[rr * 68 + CB + fr] = acch[j] + S1 * accm[j] + S2 * accl[j];
    }
    __syncthreads();

    const int r0 = w << 2;                 // 4 rows per wave (8 waves x 4 = 32)
#pragma unroll
    for (int i = 0; i < 4; ++i) {
        const int G = rowG0 + r0 + i;
        const float v = lg[(r0 + i) * 68 + l] + 0.1f * noise[(size_t)G * E + l];

        float m = v;
#pragma unroll
        for (int off = 32; off > 0; off >>= 1)
            m = fmaxf(m, __shfl_xor(m, off, 64));
        const float p = expf(v - m);
        float s = p;
#pragma unroll
        for (int off = 32; off > 0; off >>= 1)
            s += __shfl_xor(s, off, 64);
        const float prob = p / s;
        probs[(size_t)G * E + l] = prob;

        float bv = prob; int bi = l;
#pragma unroll
        for (int off = 32; off > 0; off >>= 1) {
            const float ov = __shfl_xor(bv, off, 64);
            const int   oi = __shfl_xor(bi, off, 64);
            if (ov > bv || (ov == bv && oi < bi)) { bv = ov; bi = oi; }
        }
        float cv = (l == bi) ? -INFINITY : prob;
        int ci = l;
#pragma unroll
        for (int off = 32; off > 0; off >>= 1) {
            const float ov = __shfl_xor(cv, off, 64);
            const int   oi = __shfl_xor(ci, off, 64);
            if (ov > cv || (ov == cv && oi < ci)) { cv = ov; ci = oi; }
        }

        const float sum2 = bv + cv;
        float dval = 0.f;
        if (l == bi) dval = bv / sum2;
        if (l == ci) dval = cv / sum2;
        dispatch[(size_t)G * E + l] = dval;

        if (l == 0) {
            float2 sv; sv.x = (float)bi; sv.y = (float)ci;
            *(float2*)(sel + (size_t)G * 2) = sv;
        }
    }
}

extern "C" void kernel_launch(void* const* d_in, const int* in_sizes, int n_in,
                              void* d_out, int out_size, void* d_ws, size_t ws_size,
                              hipStream_t stream) {
    const float* x     = (const float*)d_in[0];
    const float* W     = (const float*)d_in[1];
    const float* scond = (const float*)d_in[2];
    const float* noise = (const float*)d_in[3];
    const int*   sidx  = (const int*)d_in[4];

    float* out      = (float*)d_out;
    float* dispatch = out;
    float* probs    = out + (size_t)NROWS * E;
    float* sel      = out + 2 * (size_t)NROWS * E;

    (void)d_ws; (void)ws_size;   // workspace deliberately unused

    w_cvt<<<dim3(64), dim3(256), 0, stream>>>(W);
    moe_fused<<<dim3(NROWS / ROWS_PB), dim3(512), 0, stream>>>(
        x, scond, sidx, noise, dispatch, probs, sel);
}